// Round 9
// baseline (239.545 us; speedup 1.0000x reference)
//
#include <hip/hip_runtime.h>
#include <hip/hip_bf16.h>

// Problem constants: B=4, S=4096, D=2048, K=4
// out[b,s,d] = bias[d] + sum_k w[d,k] * x[b, s-3+k, d]   (zero-pad s<0)
//
// R9: defeat the register allocator's load-sinking with global_load_lds
// (fire-and-forget, no dest VGPR -> compiler cannot collapse the queue).
// Each block stages a (R+3)x256-col float4 tile into LDS (76KB, ~19
// global_load_lds_dwordx4 in flight per wave), syncs, then computes 16
// output rows from LDS. 2 blocks/CU: block A stages while block B computes.

typedef float vfloat4 __attribute__((ext_vector_type(4)));

namespace {
constexpr int B = 4;
constexpr int S = 4096;
constexpr int D = 2048;
constexpr int D4 = D / 4;          // 512 float4 per row
constexpr int R = 16;              // output rows per block
constexpr int HALO = 3;
constexpr int ROWS = R + HALO;     // 19 staged rows
constexpr int COLS = 256;          // d4 columns per block (half of D4)
constexpr int BLOCK = 256;
}

__global__ __launch_bounds__(BLOCK, 2) void causal_dwconv1d_k4(
    const vfloat4* __restrict__ x,      // [B*S*D4]
    const vfloat4* __restrict__ w4,     // [D]
    const vfloat4* __restrict__ bias4,  // [D4]
    vfloat4* __restrict__ out)          // [B*S*D4]
{
    __shared__ vfloat4 tile[ROWS][COLS];   // 19 * 256 * 16B = 77824 B

    const int tid  = threadIdx.x;
    const int wave = tid >> 6;
    const int lane = tid & 63;
    const int col0 = blockIdx.x * COLS;    // 0 or 256
    const int s0   = blockIdx.y * R;
    const int b    = blockIdx.z;

    const vfloat4* xb = x   + (size_t)b * S * D4 + col0;
    vfloat4*       ob = out + (size_t)b * S * D4 + col0;

    // Per-channel weights (independent VGPR loads; drained by the barrier).
    const int c = tid;                     // this thread's column within tile
    const vfloat4 wa = w4[(col0 + c) * 4 + 0];
    const vfloat4 wb = w4[(col0 + c) * 4 + 1];
    const vfloat4 wc = w4[(col0 + c) * 4 + 2];
    const vfloat4 wd = w4[(col0 + c) * 4 + 3];
    const vfloat4 bv = bias4[col0 + c];

    // Stage ROWS x COLS tile: 19 rows x 4 chunks of 64 float4 (1KB each).
    // LDS dest is wave-uniform base + lane*16 (HW rule); global src is
    // per-lane. Both sides contiguous -> max-width dwordx4 direct-to-LDS.
    for (int i = wave; i < ROWS * 4; i += 4) {
        const int row = i >> 2;
        const int ch  = (i & 3) * 64;
        const int s   = s0 - HALO + row;
        if (s >= 0) {
            const vfloat4* src = xb + (size_t)s * D4 + ch + lane;
            __builtin_amdgcn_global_load_lds(
                (const __attribute__((address_space(1))) void*)src,
                (__attribute__((address_space(3))) void*)&tile[row][ch],
                16, 0, 0);
        } else {
            tile[row][ch + lane] = (vfloat4)(0.f);   // causal zero-pad
        }
    }

    __syncthreads();   // drains vmcnt (global_load_lds) + lgkmcnt (ds_write)

    // Compute 16 rows from LDS with a rolling 3-register window.
    vfloat4 xm3 = tile[0][c];
    vfloat4 xm2 = tile[1][c];
    vfloat4 xm1 = tile[2][c];
#pragma unroll
    for (int r = 0; r < R; ++r) {
        const vfloat4 xc = tile[r + HALO][c];
        vfloat4 o;
        o.x = bv.x + wa.x * xm3.x + wa.y * xm2.x + wa.z * xm1.x + wa.w * xc.x;
        o.y = bv.y + wb.x * xm3.y + wb.y * xm2.y + wb.z * xm1.y + wb.w * xc.y;
        o.z = bv.z + wc.x * xm3.z + wc.y * xm2.z + wc.z * xm1.z + wc.w * xc.z;
        o.w = bv.w + wd.x * xm3.w + wd.y * xm2.w + wd.z * xm1.w + wd.w * xc.w;
        ob[(size_t)(s0 + r) * D4 + c] = o;
        xm3 = xm2; xm2 = xm1; xm1 = xc;
    }
}

extern "C" void kernel_launch(void* const* d_in, const int* in_sizes, int n_in,
                              void* d_out, int out_size, void* d_ws, size_t ws_size,
                              hipStream_t stream) {
    const vfloat4* x     = (const vfloat4*)d_in[0];
    const vfloat4* w4    = (const vfloat4*)d_in[1];
    const vfloat4* bias4 = (const vfloat4*)d_in[2];
    vfloat4* out         = (vfloat4*)d_out;

    dim3 grid(D4 / COLS, S / R, B);    // (2, 256, 4) = 2048 blocks
    dim3 block(BLOCK);
    causal_dwconv1d_k4<<<grid, block, 0, stream>>>(x, w4, bias4, out);
}